// Round 2
// baseline (1130.447 us; speedup 1.0000x reference)
//
#include <hip/hip_runtime.h>
#include <hip/hip_bf16.h>

// GCN x3 + FC on a fixed random graph.
// Strategy:
//   1. Build in-edge CSR once per call (count -> scan -> fill); dinv = rsqrt(deg+1).
//   2. Per layer: pull-based aggregation in the INPUT feature dim (8/16/32),
//      then dense per-node transform (+bias, relu).
//   3. Last transform fused with the final FC (keeps t[64] in registers).
// R1 fix: t3fc was spilling tt[64] to scratch (VGPR capped at 64 by default
// heuristic -> 2 GB of spill traffic, 560 us). __launch_bounds__(256,4)
// raises the cap to 128 VGPRs; ~110 needed -> no spill.

#define SCAN_BLOCK 256
#define SCAN_ELEMS 4   // elements per thread in scan kernels -> 1024/block

__global__ void count_kernel(const int* __restrict__ dst, int* __restrict__ deg, int E) {
    int e = blockIdx.x * blockDim.x + threadIdx.x;
    if (e < E) atomicAdd(&deg[dst[e]], 1);
}

// Per-block exclusive scan over 1024 deg entries; also emits dinv = rsqrt(deg+1).
__global__ void scan1_kernel(const int* __restrict__ deg, int* __restrict__ off,
                             int* __restrict__ bsum, float* __restrict__ dinv, int n) {
    __shared__ int sh[SCAN_BLOCK];
    int tid = threadIdx.x;
    int base = (blockIdx.x * SCAN_BLOCK + tid) * SCAN_ELEMS;
    int d[SCAN_ELEMS];
#pragma unroll
    for (int i = 0; i < SCAN_ELEMS; i++) {
        d[i] = deg[base + i];
        dinv[base + i] = rsqrtf((float)(d[i] + 1));
    }
    int s = d[0] + d[1] + d[2] + d[3];
    sh[tid] = s;
    __syncthreads();
    for (int o = 1; o < SCAN_BLOCK; o <<= 1) {
        int v = (tid >= o) ? sh[tid - o] : 0;
        __syncthreads();
        sh[tid] += v;
        __syncthreads();
    }
    int excl = sh[tid] - s;
    if (tid == SCAN_BLOCK - 1) bsum[blockIdx.x] = sh[SCAN_BLOCK - 1];
    int run = excl;
#pragma unroll
    for (int i = 0; i < SCAN_ELEMS; i++) { off[base + i] = run; run += d[i]; }
}

// Exclusive scan of the (<=256) block sums, single block.
__global__ void scan2_kernel(int* __restrict__ bsum, int nblocks) {
    __shared__ int sh[SCAN_BLOCK];
    int tid = threadIdx.x;
    int s = (tid < nblocks) ? bsum[tid] : 0;
    sh[tid] = s;
    __syncthreads();
    for (int o = 1; o < SCAN_BLOCK; o <<= 1) {
        int v = (tid >= o) ? sh[tid - o] : 0;
        __syncthreads();
        sh[tid] += v;
        __syncthreads();
    }
    if (tid < nblocks) bsum[tid] = sh[tid] - s;
}

// Add block offsets; also initialize the fill cursors.
__global__ void scan3_kernel(int* __restrict__ off, const int* __restrict__ bsum,
                             int* __restrict__ cursor) {
    int add = bsum[blockIdx.x];
    int base = (blockIdx.x * SCAN_BLOCK + threadIdx.x) * SCAN_ELEMS;
#pragma unroll
    for (int i = 0; i < SCAN_ELEMS; i++) {
        int v = off[base + i] + add;
        off[base + i] = v;
        cursor[base + i] = v;
    }
}

__global__ void fill_kernel(const int* __restrict__ src, const int* __restrict__ dst,
                            int* __restrict__ cursor, int* __restrict__ adj, int E) {
    int e = blockIdx.x * blockDim.x + threadIdx.x;
    if (e < E) {
        int d = dst[e];
        int p = atomicAdd(&cursor[d], 1);
        adj[p] = src[e];
    }
}

// Pull aggregation: out[v] = dinv[v] * (sum_{s in in(v)} dinv[s]*x[s] + dinv[v]*x[v])
// C = number of float4 chunks per feature row (F/4). C lanes cooperate per node.
template <int C>
__global__ void agg_kernel(const float* __restrict__ x, const int* __restrict__ off,
                           const int* __restrict__ adj, const float* __restrict__ dinv,
                           float* __restrict__ out, int n, int E) {
    int t = blockIdx.x * blockDim.x + threadIdx.x;
    int v = t / C;
    int c = t % C;
    if (v >= n) return;
    const float4* x4 = (const float4*)x;
    float wv = dinv[v];
    float4 xv = x4[(size_t)v * C + c];
    float4 acc;
    acc.x = wv * xv.x; acc.y = wv * xv.y; acc.z = wv * xv.z; acc.w = wv * xv.w;
    int beg = off[v];
    int end = (v == n - 1) ? E : off[v + 1];
    for (int e = beg; e < end; e++) {
        int s = adj[e];
        float ws = dinv[s];
        float4 xs = x4[(size_t)s * C + c];
        acc.x += ws * xs.x; acc.y += ws * xs.y; acc.z += ws * xs.z; acc.w += ws * xs.w;
    }
    float4 o;
    o.x = acc.x * wv; o.y = acc.y * wv; o.z = acc.z * wv; o.w = acc.w * wv;
    ((float4*)out)[(size_t)v * C + c] = o;
}

// Dense per-node transform: out[v] = act(in[v] @ W + b). W: [FIN, FOUT] row-major.
template <int FIN, int FOUT, bool RELU>
__global__ void transform_kernel(const float* __restrict__ in, const float* __restrict__ W,
                                 const float* __restrict__ b, float* __restrict__ out, int n) {
    __shared__ float Ws[FIN * FOUT];
    __shared__ float bs[FOUT];
    for (int i = threadIdx.x; i < FIN * FOUT; i += blockDim.x) Ws[i] = W[i];
    if (threadIdx.x < FOUT) bs[threadIdx.x] = b[threadIdx.x];
    __syncthreads();
    int v = blockIdx.x * blockDim.x + threadIdx.x;
    if (v >= n) return;
    float a[FIN];
    const float4* in4 = (const float4*)(in + (size_t)v * FIN);
#pragma unroll
    for (int k = 0; k < FIN / 4; k++) {
        float4 t = in4[k];
        a[4 * k] = t.x; a[4 * k + 1] = t.y; a[4 * k + 2] = t.z; a[4 * k + 3] = t.w;
    }
    float4* out4 = (float4*)(out + (size_t)v * FOUT);
#pragma unroll
    for (int j = 0; j < FOUT; j += 4) {
        float acc0 = bs[j], acc1 = bs[j + 1], acc2 = bs[j + 2], acc3 = bs[j + 3];
#pragma unroll
        for (int k = 0; k < FIN; k++) {
            float xv = a[k];
            acc0 += xv * Ws[k * FOUT + j];
            acc1 += xv * Ws[k * FOUT + j + 1];
            acc2 += xv * Ws[k * FOUT + j + 2];
            acc3 += xv * Ws[k * FOUT + j + 3];
        }
        float4 o;
        if (RELU) {
            o.x = fmaxf(acc0, 0.f); o.y = fmaxf(acc1, 0.f);
            o.z = fmaxf(acc2, 0.f); o.w = fmaxf(acc3, 0.f);
        } else {
            o.x = acc0; o.y = acc1; o.z = acc2; o.w = acc3;
        }
        out4[j / 4] = o;
    }
}

// Fused: out[v] = relu(a3[v] @ W3 + b3) @ Wfc + bfc  (32 -> 64 -> 64)
// __launch_bounds__(256,4): cap = 128 VGPR/thread; tt[64]+a[32]+acc ~ 110 -> no spill.
__global__ void __launch_bounds__(256, 4)
t3fc_kernel(const float* __restrict__ in,
            const float* __restrict__ W3, const float* __restrict__ b3,
            const float* __restrict__ Wf, const float* __restrict__ bf,
            float* __restrict__ out, int n) {
    __shared__ float W3s[32 * 64];
    __shared__ float Wfs[64 * 64];
    __shared__ float b3s[64];
    __shared__ float bfs[64];
    for (int i = threadIdx.x; i < 32 * 64; i += blockDim.x) W3s[i] = W3[i];
    for (int i = threadIdx.x; i < 64 * 64; i += blockDim.x) Wfs[i] = Wf[i];
    if (threadIdx.x < 64) { b3s[threadIdx.x] = b3[threadIdx.x]; bfs[threadIdx.x] = bf[threadIdx.x]; }
    __syncthreads();
    int v = blockIdx.x * blockDim.x + threadIdx.x;
    if (v >= n) return;
    float tt[64];
    {   // scope a[] so it is dead before the FC loop (peak pressure ~110 VGPR)
        float a[32];
        const float4* in4 = (const float4*)(in + (size_t)v * 32);
#pragma unroll
        for (int k = 0; k < 8; k++) {
            float4 t = in4[k];
            a[4 * k] = t.x; a[4 * k + 1] = t.y; a[4 * k + 2] = t.z; a[4 * k + 3] = t.w;
        }
#pragma unroll
        for (int j = 0; j < 64; j++) {
            float acc = b3s[j];
#pragma unroll
            for (int k = 0; k < 32; k++) acc += a[k] * W3s[k * 64 + j];
            tt[j] = fmaxf(acc, 0.f);
        }
    }
    float4* out4 = (float4*)(out + (size_t)v * 64);
#pragma unroll
    for (int j = 0; j < 64; j += 4) {
        float acc0 = bfs[j], acc1 = bfs[j + 1], acc2 = bfs[j + 2], acc3 = bfs[j + 3];
#pragma unroll
        for (int k = 0; k < 64; k++) {
            float tv = tt[k];
            acc0 += tv * Wfs[k * 64 + j];
            acc1 += tv * Wfs[k * 64 + j + 1];
            acc2 += tv * Wfs[k * 64 + j + 2];
            acc3 += tv * Wfs[k * 64 + j + 3];
        }
        float4 o;
        o.x = acc0; o.y = acc1; o.z = acc2; o.w = acc3;
        out4[j / 4] = o;
    }
}

extern "C" void kernel_launch(void* const* d_in, const int* in_sizes, int n_in,
                              void* d_out, int out_size, void* d_ws, size_t ws_size,
                              hipStream_t stream) {
    const float* x  = (const float*)d_in[0];
    const float* W1 = (const float*)d_in[1];
    const float* b1 = (const float*)d_in[2];
    const float* W2 = (const float*)d_in[3];
    const float* b2 = (const float*)d_in[4];
    const float* W3 = (const float*)d_in[5];
    const float* b3 = (const float*)d_in[6];
    const float* Wf = (const float*)d_in[7];
    const float* bf = (const float*)d_in[8];
    const int*   ei = (const int*)d_in[9];

    const int N = in_sizes[0] / 8;   // 262144
    const int E = in_sizes[9] / 2;   // 2097152
    const int* srcv = ei;
    const int* dstv = ei + E;

    // Workspace layout
    char* p = (char*)d_ws;
    int*   off    = (int*)p;            p += (size_t)N * 4;
    int*   deg    = (int*)p;            p += (size_t)N * 4;
    int*   cursor = (int*)p;            p += (size_t)N * 4;
    float* dinv   = (float*)p;          p += (size_t)N * 4;
    int*   bsum   = (int*)p;            p += 1024;            // up to 256 block sums
    int*   adj    = (int*)p;            p += (size_t)E * 4;
    float* bufA   = (float*)p;          p += (size_t)N * 32 * 4;
    float* bufB   = (float*)p;          p += (size_t)N * 32 * 4;

    hipMemsetAsync(deg, 0, (size_t)N * 4, stream);

    int eb = (E + 255) / 256;
    count_kernel<<<eb, 256, 0, stream>>>(dstv, deg, E);

    int sb = N / (SCAN_BLOCK * SCAN_ELEMS);  // 256 blocks at N=262144
    scan1_kernel<<<sb, SCAN_BLOCK, 0, stream>>>(deg, off, bsum, dinv, N);
    scan2_kernel<<<1, SCAN_BLOCK, 0, stream>>>(bsum, sb);
    scan3_kernel<<<sb, SCAN_BLOCK, 0, stream>>>(off, bsum, cursor);
    fill_kernel<<<eb, 256, 0, stream>>>(srcv, dstv, cursor, adj, E);

    // Layer 1: aggregate x [N,8] -> bufA, transform 8->16 -> bufB
    agg_kernel<2><<<(N * 2 + 255) / 256, 256, 0, stream>>>(x, off, adj, dinv, bufA, N, E);
    transform_kernel<8, 16, true><<<(N + 255) / 256, 256, 0, stream>>>(bufA, W1, b1, bufB, N);

    // Layer 2: aggregate h1 [N,16] -> bufA, transform 16->32 -> bufB
    agg_kernel<4><<<(N * 4 + 255) / 256, 256, 0, stream>>>(bufB, off, adj, dinv, bufA, N, E);
    transform_kernel<16, 32, true><<<(N + 255) / 256, 256, 0, stream>>>(bufA, W2, b2, bufB, N);

    // Layer 3: aggregate h2 [N,32] -> bufA, fused transform 32->64 + FC 64->64 -> out
    agg_kernel<8><<<(N * 8 + 255) / 256, 256, 0, stream>>>(bufB, off, adj, dinv, bufA, N, E);
    t3fc_kernel<<<(N + 255) / 256, 256, 0, stream>>>(bufA, W3, b3, Wf, bf, (float*)d_out, N);
}

// Round 3
// 583.252 us; speedup vs baseline: 1.9382x; 1.9382x over previous
//
#include <hip/hip_runtime.h>
#include <hip/hip_bf16.h>

// GCN x3 + FC on a fixed random graph.
// Strategy:
//   1. Build in-edge CSR once per call (count -> scan -> fill); dinv = rsqrt(deg+1).
//   2. Per layer: pull-based aggregation in the INPUT feature dim (8/16/32),
//      then dense per-node transform (+bias, relu).
//   3. Last transform fused with the final FC.
// R2 fix: the fused t3fc had per-thread tt[64]/a[32] arrays; compiler never
// unrolled the 64x64 FMA nest, arrays stayed in scratch -> 2.1 GB spill
// traffic (launch_bounds couldn't help; it's an SROA failure, not a VGPR cap).
// New t3fc is block-cooperative: inputs + relu(h3) staged in LDS (padded),
// each thread owns a 2-node x 4-col register tile. No per-thread arrays.

#define SCAN_BLOCK 256
#define SCAN_ELEMS 4   // elements per thread in scan kernels -> 1024/block

__global__ void count_kernel(const int* __restrict__ dst, int* __restrict__ deg, int E) {
    int e = blockIdx.x * blockDim.x + threadIdx.x;
    if (e < E) atomicAdd(&deg[dst[e]], 1);
}

// Per-block exclusive scan over 1024 deg entries; also emits dinv = rsqrt(deg+1).
__global__ void scan1_kernel(const int* __restrict__ deg, int* __restrict__ off,
                             int* __restrict__ bsum, float* __restrict__ dinv, int n) {
    __shared__ int sh[SCAN_BLOCK];
    int tid = threadIdx.x;
    int base = (blockIdx.x * SCAN_BLOCK + tid) * SCAN_ELEMS;
    int d[SCAN_ELEMS];
#pragma unroll
    for (int i = 0; i < SCAN_ELEMS; i++) {
        d[i] = deg[base + i];
        dinv[base + i] = rsqrtf((float)(d[i] + 1));
    }
    int s = d[0] + d[1] + d[2] + d[3];
    sh[tid] = s;
    __syncthreads();
    for (int o = 1; o < SCAN_BLOCK; o <<= 1) {
        int v = (tid >= o) ? sh[tid - o] : 0;
        __syncthreads();
        sh[tid] += v;
        __syncthreads();
    }
    int excl = sh[tid] - s;
    if (tid == SCAN_BLOCK - 1) bsum[blockIdx.x] = sh[SCAN_BLOCK - 1];
    int run = excl;
#pragma unroll
    for (int i = 0; i < SCAN_ELEMS; i++) { off[base + i] = run; run += d[i]; }
}

// Exclusive scan of the (<=256) block sums, single block.
__global__ void scan2_kernel(int* __restrict__ bsum, int nblocks) {
    __shared__ int sh[SCAN_BLOCK];
    int tid = threadIdx.x;
    int s = (tid < nblocks) ? bsum[tid] : 0;
    sh[tid] = s;
    __syncthreads();
    for (int o = 1; o < SCAN_BLOCK; o <<= 1) {
        int v = (tid >= o) ? sh[tid - o] : 0;
        __syncthreads();
        sh[tid] += v;
        __syncthreads();
    }
    if (tid < nblocks) bsum[tid] = sh[tid] - s;
}

// Add block offsets; also initialize the fill cursors.
__global__ void scan3_kernel(int* __restrict__ off, const int* __restrict__ bsum,
                             int* __restrict__ cursor) {
    int add = bsum[blockIdx.x];
    int base = (blockIdx.x * SCAN_BLOCK + threadIdx.x) * SCAN_ELEMS;
#pragma unroll
    for (int i = 0; i < SCAN_ELEMS; i++) {
        int v = off[base + i] + add;
        off[base + i] = v;
        cursor[base + i] = v;
    }
}

__global__ void fill_kernel(const int* __restrict__ src, const int* __restrict__ dst,
                            int* __restrict__ cursor, int* __restrict__ adj, int E) {
    int e = blockIdx.x * blockDim.x + threadIdx.x;
    if (e < E) {
        int d = dst[e];
        int p = atomicAdd(&cursor[d], 1);
        adj[p] = src[e];
    }
}

// Pull aggregation: out[v] = dinv[v] * (sum_{s in in(v)} dinv[s]*x[s] + dinv[v]*x[v])
// C = number of float4 chunks per feature row (F/4). C lanes cooperate per node.
template <int C>
__global__ void agg_kernel(const float* __restrict__ x, const int* __restrict__ off,
                           const int* __restrict__ adj, const float* __restrict__ dinv,
                           float* __restrict__ out, int n, int E) {
    int t = blockIdx.x * blockDim.x + threadIdx.x;
    int v = t / C;
    int c = t % C;
    if (v >= n) return;
    const float4* x4 = (const float4*)x;
    float wv = dinv[v];
    float4 xv = x4[(size_t)v * C + c];
    float4 acc;
    acc.x = wv * xv.x; acc.y = wv * xv.y; acc.z = wv * xv.z; acc.w = wv * xv.w;
    int beg = off[v];
    int end = (v == n - 1) ? E : off[v + 1];
    for (int e = beg; e < end; e++) {
        int s = adj[e];
        float ws = dinv[s];
        float4 xs = x4[(size_t)s * C + c];
        acc.x += ws * xs.x; acc.y += ws * xs.y; acc.z += ws * xs.z; acc.w += ws * xs.w;
    }
    float4 o;
    o.x = acc.x * wv; o.y = acc.y * wv; o.z = acc.z * wv; o.w = acc.w * wv;
    ((float4*)out)[(size_t)v * C + c] = o;
}

// Dense per-node transform: out[v] = act(in[v] @ W + b). W: [FIN, FOUT] row-major.
// Only used with FIN<=16 (small per-thread array, unrolls fully).
template <int FIN, int FOUT, bool RELU>
__global__ void transform_kernel(const float* __restrict__ in, const float* __restrict__ W,
                                 const float* __restrict__ b, float* __restrict__ out, int n) {
    __shared__ float Ws[FIN * FOUT];
    __shared__ float bs[FOUT];
    for (int i = threadIdx.x; i < FIN * FOUT; i += blockDim.x) Ws[i] = W[i];
    if (threadIdx.x < FOUT) bs[threadIdx.x] = b[threadIdx.x];
    __syncthreads();
    int v = blockIdx.x * blockDim.x + threadIdx.x;
    if (v >= n) return;
    float a[FIN];
    const float4* in4 = (const float4*)(in + (size_t)v * FIN);
#pragma unroll
    for (int k = 0; k < FIN / 4; k++) {
        float4 t = in4[k];
        a[4 * k] = t.x; a[4 * k + 1] = t.y; a[4 * k + 2] = t.z; a[4 * k + 3] = t.w;
    }
    float4* out4 = (float4*)(out + (size_t)v * FOUT);
#pragma unroll
    for (int j = 0; j < FOUT; j += 4) {
        float acc0 = bs[j], acc1 = bs[j + 1], acc2 = bs[j + 2], acc3 = bs[j + 3];
#pragma unroll
        for (int k = 0; k < FIN; k++) {
            float xv = a[k];
            acc0 += xv * Ws[k * FOUT + j];
            acc1 += xv * Ws[k * FOUT + j + 1];
            acc2 += xv * Ws[k * FOUT + j + 2];
            acc3 += xv * Ws[k * FOUT + j + 3];
        }
        float4 o;
        if (RELU) {
            o.x = fmaxf(acc0, 0.f); o.y = fmaxf(acc1, 0.f);
            o.z = fmaxf(acc2, 0.f); o.w = fmaxf(acc3, 0.f);
        } else {
            o.x = acc0; o.y = acc1; o.z = acc2; o.w = acc3;
        }
        out4[j / 4] = o;
    }
}

// Fused: out[v] = relu(a3[v] @ W3 + b3) @ Wfc + bfc  (32 -> 64 -> 64)
// Block-cooperative: 32 nodes/block. Inputs and relu(h3) staged in LDS
// (row pads 33/65 -> conflict-free broadcasts). Each thread: j-group j0=4*tx,
// node pair (ty, ty+16); 8 accumulators, float4 weight reads. No arrays.
#define T3_NODES 32
__global__ void __launch_bounds__(256)
t3fc_kernel(const float* __restrict__ in,
            const float* __restrict__ W3, const float* __restrict__ b3,
            const float* __restrict__ Wf, const float* __restrict__ bf,
            float* __restrict__ out, int n) {
    __shared__ float W3s[32 * 64];           // [k][j], 8 KB
    __shared__ float Wfs[64 * 64];           // [k][j], 16 KB
    __shared__ float b3s[64], bfs[64];
    __shared__ float ins[T3_NODES][33];      // staged input rows (+1 pad)
    __shared__ float tts[T3_NODES][65];      // relu(h3) rows (+1 pad)
    const int tid = threadIdx.x;
    for (int i = tid; i < 32 * 64; i += 256) W3s[i] = W3[i];
    for (int i = tid; i < 64 * 64; i += 256) Wfs[i] = Wf[i];
    if (tid < 64) { b3s[tid] = b3[tid]; bfs[tid] = bf[tid]; }
    const int vbase = blockIdx.x * T3_NODES;
    {   // stage inputs: T3_NODES*8 float4 = 256 loads, one per thread
        const float4* g = (const float4*)(in + (size_t)vbase * 32);
        float4 t = g[tid];
        int v = tid >> 3, c = (tid & 7) * 4;
        ins[v][c] = t.x; ins[v][c + 1] = t.y; ins[v][c + 2] = t.z; ins[v][c + 3] = t.w;
    }
    __syncthreads();
    const int tx = tid & 15;     // j-group
    const int ty = tid >> 4;     // node
    const int j0 = tx * 4;
    // phase 1: tt[v][j0..j0+3] = relu(b3 + a[v] @ W3) for v = ty, ty+16
    {
        float a00 = b3s[j0], a01 = b3s[j0 + 1], a02 = b3s[j0 + 2], a03 = b3s[j0 + 3];
        float a10 = a00, a11 = a01, a12 = a02, a13 = a03;
#pragma unroll
        for (int k = 0; k < 32; k++) {
            float4 w = *(const float4*)&W3s[k * 64 + j0];
            float x0 = ins[ty][k];
            float x1 = ins[ty + 16][k];
            a00 += x0 * w.x; a01 += x0 * w.y; a02 += x0 * w.z; a03 += x0 * w.w;
            a10 += x1 * w.x; a11 += x1 * w.y; a12 += x1 * w.z; a13 += x1 * w.w;
        }
        tts[ty][j0]      = fmaxf(a00, 0.f); tts[ty][j0 + 1]      = fmaxf(a01, 0.f);
        tts[ty][j0 + 2]  = fmaxf(a02, 0.f); tts[ty][j0 + 3]      = fmaxf(a03, 0.f);
        tts[ty + 16][j0] = fmaxf(a10, 0.f); tts[ty + 16][j0 + 1] = fmaxf(a11, 0.f);
        tts[ty + 16][j0 + 2] = fmaxf(a12, 0.f); tts[ty + 16][j0 + 3] = fmaxf(a13, 0.f);
    }
    __syncthreads();
    // phase 2: out[v][j0..j0+3] = bf + tt[v] @ Wf
    {
        float a00 = bfs[j0], a01 = bfs[j0 + 1], a02 = bfs[j0 + 2], a03 = bfs[j0 + 3];
        float a10 = a00, a11 = a01, a12 = a02, a13 = a03;
#pragma unroll
        for (int k = 0; k < 64; k++) {
            float4 w = *(const float4*)&Wfs[k * 64 + j0];
            float x0 = tts[ty][k];
            float x1 = tts[ty + 16][k];
            a00 += x0 * w.x; a01 += x0 * w.y; a02 += x0 * w.z; a03 += x0 * w.w;
            a10 += x1 * w.x; a11 += x1 * w.y; a12 += x1 * w.z; a13 += x1 * w.w;
        }
        float4 o0; o0.x = a00; o0.y = a01; o0.z = a02; o0.w = a03;
        float4 o1; o1.x = a10; o1.y = a11; o1.z = a12; o1.w = a13;
        *(float4*)(out + ((size_t)(vbase + ty)) * 64 + j0) = o0;
        *(float4*)(out + ((size_t)(vbase + ty + 16)) * 64 + j0) = o1;
    }
}

extern "C" void kernel_launch(void* const* d_in, const int* in_sizes, int n_in,
                              void* d_out, int out_size, void* d_ws, size_t ws_size,
                              hipStream_t stream) {
    const float* x  = (const float*)d_in[0];
    const float* W1 = (const float*)d_in[1];
    const float* b1 = (const float*)d_in[2];
    const float* W2 = (const float*)d_in[3];
    const float* b2 = (const float*)d_in[4];
    const float* W3 = (const float*)d_in[5];
    const float* b3 = (const float*)d_in[6];
    const float* Wf = (const float*)d_in[7];
    const float* bf = (const float*)d_in[8];
    const int*   ei = (const int*)d_in[9];

    const int N = in_sizes[0] / 8;   // 262144
    const int E = in_sizes[9] / 2;   // 2097152
    const int* srcv = ei;
    const int* dstv = ei + E;

    // Workspace layout
    char* p = (char*)d_ws;
    int*   off    = (int*)p;            p += (size_t)N * 4;
    int*   deg    = (int*)p;            p += (size_t)N * 4;
    int*   cursor = (int*)p;            p += (size_t)N * 4;
    float* dinv   = (float*)p;          p += (size_t)N * 4;
    int*   bsum   = (int*)p;            p += 1024;            // up to 256 block sums
    int*   adj    = (int*)p;            p += (size_t)E * 4;
    float* bufA   = (float*)p;          p += (size_t)N * 32 * 4;
    float* bufB   = (float*)p;          p += (size_t)N * 32 * 4;

    hipMemsetAsync(deg, 0, (size_t)N * 4, stream);

    int eb = (E + 255) / 256;
    count_kernel<<<eb, 256, 0, stream>>>(dstv, deg, E);

    int sb = N / (SCAN_BLOCK * SCAN_ELEMS);  // 256 blocks at N=262144
    scan1_kernel<<<sb, SCAN_BLOCK, 0, stream>>>(deg, off, bsum, dinv, N);
    scan2_kernel<<<1, SCAN_BLOCK, 0, stream>>>(bsum, sb);
    scan3_kernel<<<sb, SCAN_BLOCK, 0, stream>>>(off, bsum, cursor);
    fill_kernel<<<eb, 256, 0, stream>>>(srcv, dstv, cursor, adj, E);

    // Layer 1: aggregate x [N,8] -> bufA, transform 8->16 -> bufB
    agg_kernel<2><<<(N * 2 + 255) / 256, 256, 0, stream>>>(x, off, adj, dinv, bufA, N, E);
    transform_kernel<8, 16, true><<<(N + 255) / 256, 256, 0, stream>>>(bufA, W1, b1, bufB, N);

    // Layer 2: aggregate h1 [N,16] -> bufA, transform 16->32 -> bufB
    agg_kernel<4><<<(N * 4 + 255) / 256, 256, 0, stream>>>(bufB, off, adj, dinv, bufA, N, E);
    transform_kernel<16, 32, true><<<(N + 255) / 256, 256, 0, stream>>>(bufA, W2, b2, bufB, N);

    // Layer 3: aggregate h2 [N,32] -> bufA, fused transform 32->64 + FC 64->64 -> out
    agg_kernel<8><<<(N * 8 + 255) / 256, 256, 0, stream>>>(bufB, off, adj, dinv, bufA, N, E);
    t3fc_kernel<<<(N / T3_NODES), 256, 0, stream>>>(bufA, W3, b3, Wf, bf, (float*)d_out, N);
}

// Round 4
// 457.334 us; speedup vs baseline: 2.4718x; 1.2753x over previous
//
#include <hip/hip_runtime.h>
#include <hip/hip_bf16.h>

// GCN x3 + FC on a fixed random graph.
//   1. Bucket-partition CSR build: LDS-histogram -> scan -> LDS counting-sort
//      partition -> per-bucket build (LDS atomics only, coalesced global I/O).
//   2. Per layer: pull aggregation in the INPUT dim (8/16/32), dense transform.
//   3. Last transform fused with FC (block-cooperative, no per-thread arrays).
// R3 fix history: t3fc scratch spill fixed in R2 (block-cooperative).
// R4: fill_kernel was 171 us — 2M contended global atomics + 139 MB HBM write
// amplification from scattered 4B adj stores. Replaced count/scan/fill with
// a 4-kernel bucket pipeline: global atomics 2M->~400K (bulk, uncontended),
// adj writes land in per-bucket 32KB windows (single-XCD L2, write-back once).

#define NB   256     // dst buckets
#define NPB  1024    // nodes per bucket (N = 262144 = NB * NPB)
#define TILE 4096    // edges per partition tile

// ---- P1: global bucket histogram -------------------------------------------
__global__ void hist_kernel(const int* __restrict__ dst, int* __restrict__ ghist,
                            int E, int shift) {
    __shared__ int h[NB];
    int tid = threadIdx.x;
    h[tid] = 0;
    __syncthreads();
    int base = blockIdx.x * TILE;
    int cnt = min(TILE, E - base);
    for (int i = tid; i < cnt; i += 256)
        atomicAdd(&h[dst[base + i] >> shift], 1);
    __syncthreads();
    int v = h[tid];
    if (v) atomicAdd(&ghist[tid], v);
}

// ---- P2: scan bucket counts -> bbase[NB+1], init gcursor -------------------
__global__ void bscan_kernel(const int* __restrict__ ghist, int* __restrict__ bbase,
                             int* __restrict__ gcursor) {
    __shared__ int sh[NB];
    int tid = threadIdx.x;
    int v = ghist[tid];
    sh[tid] = v;
    __syncthreads();
    for (int o = 1; o < NB; o <<= 1) {
        int t = (tid >= o) ? sh[tid - o] : 0;
        __syncthreads();
        sh[tid] += t;
        __syncthreads();
    }
    int incl = sh[tid];
    bbase[tid] = incl - v;
    gcursor[tid] = incl - v;
    if (tid == NB - 1) bbase[NB] = incl;
}

// ---- P3: partition edges into bucket-sorted (src, dst_local) ---------------
__global__ void __launch_bounds__(256)
partition_kernel(const int* __restrict__ src, const int* __restrict__ dst,
                 int* __restrict__ gcursor, int* __restrict__ bsrc,
                 unsigned short* __restrict__ bdl, int E, int shift, int mask) {
    __shared__ int h[NB], st[NB], gp[NB];
    __shared__ unsigned short rk[TILE];
    __shared__ int sd[TILE];
    __shared__ int ss[TILE];
    int tid = threadIdx.x;
    h[tid] = 0;
    __syncthreads();
    int base = blockIdx.x * TILE;
    int cnt = min(TILE, E - base);
    // phase 1: per-tile bucket ranks
    for (int i = tid; i < cnt; i += 256)
        rk[i] = (unsigned short)atomicAdd(&h[dst[base + i] >> shift], 1);
    __syncthreads();
    // phase 2: exclusive scan of h -> st; bulk global cursor bump -> gp
    int hv = h[tid];
    st[tid] = hv;
    __syncthreads();
    for (int o = 1; o < NB; o <<= 1) {
        int t = (tid >= o) ? st[tid - o] : 0;
        __syncthreads();
        st[tid] += t;
        __syncthreads();
    }
    st[tid] -= hv;   // own slot only; no cross-reads until next sync
    gp[tid] = hv ? atomicAdd(&gcursor[tid], hv) : 0;
    __syncthreads();
    // phase 3: counting-sort into LDS
    for (int i = tid; i < cnt; i += 256) {
        int d = dst[base + i];
        int b = d >> shift;
        int pos = st[b] + rk[i];
        sd[pos] = d;
        ss[pos] = src[base + i];
    }
    __syncthreads();
    // phase 4: bucket-contiguous flush (coalesced runs)
    for (int i = tid; i < cnt; i += 256) {
        int d = sd[i];
        int b = d >> shift;
        int g = gp[b] + (i - st[b]);
        bsrc[g] = ss[i];
        bdl[g] = (unsigned short)(d & mask);
    }
}

// ---- P4: per-bucket CSR build: deg -> off/dinv/cursors -> adj --------------
__global__ void __launch_bounds__(256)
build_kernel(const int* __restrict__ bbase, const int* __restrict__ bsrc,
             const unsigned short* __restrict__ bdl,
             int* __restrict__ off, float* __restrict__ dinv, int* __restrict__ adj) {
    __shared__ int deg1[NPB];
    __shared__ int cur[NPB];
    __shared__ int bs[256];
    int tid = threadIdx.x;
    int b = blockIdx.x;
    int s = bbase[b], e = bbase[b + 1];
    int base = tid * 4;
#pragma unroll
    for (int i = 0; i < 4; i++) deg1[base + i] = 0;
    __syncthreads();
    for (int i = s + tid; i < e; i += 256)
        atomicAdd(&deg1[bdl[i]], 1);
    __syncthreads();
    int d0 = deg1[base], d1 = deg1[base + 1], d2 = deg1[base + 2], d3 = deg1[base + 3];
    int th = d0 + d1 + d2 + d3;
    bs[tid] = th;
    __syncthreads();
    for (int o = 1; o < 256; o <<= 1) {
        int t = (tid >= o) ? bs[tid - o] : 0;
        __syncthreads();
        bs[tid] += t;
        __syncthreads();
    }
    int run = s + bs[tid] - th;
    int vb = b * NPB + base;
    off[vb]     = run; cur[base]     = run; dinv[vb]     = rsqrtf((float)(d0 + 1)); run += d0;
    off[vb + 1] = run; cur[base + 1] = run; dinv[vb + 1] = rsqrtf((float)(d1 + 1)); run += d1;
    off[vb + 2] = run; cur[base + 2] = run; dinv[vb + 2] = rsqrtf((float)(d2 + 1)); run += d2;
    off[vb + 3] = run; cur[base + 3] = run; dinv[vb + 3] = rsqrtf((float)(d3 + 1)); run += d3;
    __syncthreads();
    for (int i = s + tid; i < e; i += 256) {
        int p = atomicAdd(&cur[bdl[i]], 1);
        adj[p] = bsrc[i];   // scattered only within this bucket's 32KB window
    }
}

// ---- Pull aggregation ------------------------------------------------------
// out[v] = dinv[v] * (sum_{s in in(v)} dinv[s]*x[s] + dinv[v]*x[v])
template <int C>
__global__ void agg_kernel(const float* __restrict__ x, const int* __restrict__ off,
                           const int* __restrict__ adj, const float* __restrict__ dinv,
                           float* __restrict__ out, int n, int E) {
    int t = blockIdx.x * blockDim.x + threadIdx.x;
    int v = t / C;
    int c = t % C;
    if (v >= n) return;
    const float4* x4 = (const float4*)x;
    float wv = dinv[v];
    float4 xv = x4[(size_t)v * C + c];
    float4 acc;
    acc.x = wv * xv.x; acc.y = wv * xv.y; acc.z = wv * xv.z; acc.w = wv * xv.w;
    int beg = off[v];
    int end = (v == n - 1) ? E : off[v + 1];
    for (int e = beg; e < end; e++) {
        int s = adj[e];
        float ws = dinv[s];
        float4 xs = x4[(size_t)s * C + c];
        acc.x += ws * xs.x; acc.y += ws * xs.y; acc.z += ws * xs.z; acc.w += ws * xs.w;
    }
    float4 o;
    o.x = acc.x * wv; o.y = acc.y * wv; o.z = acc.z * wv; o.w = acc.w * wv;
    ((float4*)out)[(size_t)v * C + c] = o;
}

// ---- Dense per-node transform (FIN<=16: unrolls fully) ---------------------
template <int FIN, int FOUT, bool RELU>
__global__ void transform_kernel(const float* __restrict__ in, const float* __restrict__ W,
                                 const float* __restrict__ b, float* __restrict__ out, int n) {
    __shared__ float Ws[FIN * FOUT];
    __shared__ float bs[FOUT];
    for (int i = threadIdx.x; i < FIN * FOUT; i += blockDim.x) Ws[i] = W[i];
    if (threadIdx.x < FOUT) bs[threadIdx.x] = b[threadIdx.x];
    __syncthreads();
    int v = blockIdx.x * blockDim.x + threadIdx.x;
    if (v >= n) return;
    float a[FIN];
    const float4* in4 = (const float4*)(in + (size_t)v * FIN);
#pragma unroll
    for (int k = 0; k < FIN / 4; k++) {
        float4 t = in4[k];
        a[4 * k] = t.x; a[4 * k + 1] = t.y; a[4 * k + 2] = t.z; a[4 * k + 3] = t.w;
    }
    float4* out4 = (float4*)(out + (size_t)v * FOUT);
#pragma unroll
    for (int j = 0; j < FOUT; j += 4) {
        float acc0 = bs[j], acc1 = bs[j + 1], acc2 = bs[j + 2], acc3 = bs[j + 3];
#pragma unroll
        for (int k = 0; k < FIN; k++) {
            float xv = a[k];
            acc0 += xv * Ws[k * FOUT + j];
            acc1 += xv * Ws[k * FOUT + j + 1];
            acc2 += xv * Ws[k * FOUT + j + 2];
            acc3 += xv * Ws[k * FOUT + j + 3];
        }
        float4 o;
        if (RELU) {
            o.x = fmaxf(acc0, 0.f); o.y = fmaxf(acc1, 0.f);
            o.z = fmaxf(acc2, 0.f); o.w = fmaxf(acc3, 0.f);
        } else {
            o.x = acc0; o.y = acc1; o.z = acc2; o.w = acc3;
        }
        out4[j / 4] = o;
    }
}

// ---- Fused layer-3 transform + FC (block-cooperative) ----------------------
#define T3_NODES 32
__global__ void __launch_bounds__(256)
t3fc_kernel(const float* __restrict__ in,
            const float* __restrict__ W3, const float* __restrict__ b3,
            const float* __restrict__ Wf, const float* __restrict__ bf,
            float* __restrict__ out, int n) {
    __shared__ float W3s[32 * 64];
    __shared__ float Wfs[64 * 64];
    __shared__ float b3s[64], bfs[64];
    __shared__ float ins[T3_NODES][33];
    __shared__ float tts[T3_NODES][65];
    const int tid = threadIdx.x;
    for (int i = tid; i < 32 * 64; i += 256) W3s[i] = W3[i];
    for (int i = tid; i < 64 * 64; i += 256) Wfs[i] = Wf[i];
    if (tid < 64) { b3s[tid] = b3[tid]; bfs[tid] = bf[tid]; }
    const int vbase = blockIdx.x * T3_NODES;
    {
        const float4* g = (const float4*)(in + (size_t)vbase * 32);
        float4 t = g[tid];
        int v = tid >> 3, c = (tid & 7) * 4;
        ins[v][c] = t.x; ins[v][c + 1] = t.y; ins[v][c + 2] = t.z; ins[v][c + 3] = t.w;
    }
    __syncthreads();
    const int tx = tid & 15;
    const int ty = tid >> 4;
    const int j0 = tx * 4;
    {
        float a00 = b3s[j0], a01 = b3s[j0 + 1], a02 = b3s[j0 + 2], a03 = b3s[j0 + 3];
        float a10 = a00, a11 = a01, a12 = a02, a13 = a03;
#pragma unroll
        for (int k = 0; k < 32; k++) {
            float4 w = *(const float4*)&W3s[k * 64 + j0];
            float x0 = ins[ty][k];
            float x1 = ins[ty + 16][k];
            a00 += x0 * w.x; a01 += x0 * w.y; a02 += x0 * w.z; a03 += x0 * w.w;
            a10 += x1 * w.x; a11 += x1 * w.y; a12 += x1 * w.z; a13 += x1 * w.w;
        }
        tts[ty][j0]          = fmaxf(a00, 0.f); tts[ty][j0 + 1]      = fmaxf(a01, 0.f);
        tts[ty][j0 + 2]      = fmaxf(a02, 0.f); tts[ty][j0 + 3]      = fmaxf(a03, 0.f);
        tts[ty + 16][j0]     = fmaxf(a10, 0.f); tts[ty + 16][j0 + 1] = fmaxf(a11, 0.f);
        tts[ty + 16][j0 + 2] = fmaxf(a12, 0.f); tts[ty + 16][j0 + 3] = fmaxf(a13, 0.f);
    }
    __syncthreads();
    {
        float a00 = bfs[j0], a01 = bfs[j0 + 1], a02 = bfs[j0 + 2], a03 = bfs[j0 + 3];
        float a10 = a00, a11 = a01, a12 = a02, a13 = a03;
#pragma unroll
        for (int k = 0; k < 64; k++) {
            float4 w = *(const float4*)&Wfs[k * 64 + j0];
            float x0 = tts[ty][k];
            float x1 = tts[ty + 16][k];
            a00 += x0 * w.x; a01 += x0 * w.y; a02 += x0 * w.z; a03 += x0 * w.w;
            a10 += x1 * w.x; a11 += x1 * w.y; a12 += x1 * w.z; a13 += x1 * w.w;
        }
        float4 o0; o0.x = a00; o0.y = a01; o0.z = a02; o0.w = a03;
        float4 o1; o1.x = a10; o1.y = a11; o1.z = a12; o1.w = a13;
        *(float4*)(out + ((size_t)(vbase + ty)) * 64 + j0) = o0;
        *(float4*)(out + ((size_t)(vbase + ty + 16)) * 64 + j0) = o1;
    }
}

extern "C" void kernel_launch(void* const* d_in, const int* in_sizes, int n_in,
                              void* d_out, int out_size, void* d_ws, size_t ws_size,
                              hipStream_t stream) {
    const float* x  = (const float*)d_in[0];
    const float* W1 = (const float*)d_in[1];
    const float* b1 = (const float*)d_in[2];
    const float* W2 = (const float*)d_in[3];
    const float* b2 = (const float*)d_in[4];
    const float* W3 = (const float*)d_in[5];
    const float* b3 = (const float*)d_in[6];
    const float* Wf = (const float*)d_in[7];
    const float* bf = (const float*)d_in[8];
    const int*   ei = (const int*)d_in[9];

    const int N = in_sizes[0] / 8;   // 262144
    const int E = in_sizes[9] / 2;   // 2097152
    const int* srcv = ei;
    const int* dstv = ei + E;
    const int shift = 10;            // log2(NPB), N = NB * NPB

    // Workspace layout
    char* p = (char*)d_ws;
    int*   off    = (int*)p;            p += (size_t)N * 4;
    float* dinv   = (float*)p;          p += (size_t)N * 4;
    int*   adj    = (int*)p;            p += (size_t)E * 4;
    int*   ghist  = (int*)p;            p += NB * 4;
    int*   bbase  = (int*)p;            p += (NB + 1) * 4;
    int*   gcur   = (int*)p;            p += NB * 4 + 4;      // pad to 8B
    float* bufA   = (float*)p;          p += (size_t)N * 32 * 4;
    float* bufB   = (float*)p;          p += (size_t)N * 32 * 4;
    // binned edge arrays alias bufB (dead until transform_kernel<8,16> writes it)
    int*            bsrc = (int*)bufB;
    unsigned short* bdl  = (unsigned short*)(bufB + (size_t)E);

    hipMemsetAsync(ghist, 0, NB * 4, stream);

    int nt = (E + TILE - 1) / TILE;  // 512 tiles
    hist_kernel<<<nt, 256, 0, stream>>>(dstv, ghist, E, shift);
    bscan_kernel<<<1, NB, 0, stream>>>(ghist, bbase, gcur);
    partition_kernel<<<nt, 256, 0, stream>>>(srcv, dstv, gcur, bsrc, bdl, E, shift, NPB - 1);
    build_kernel<<<NB, 256, 0, stream>>>(bbase, bsrc, bdl, off, dinv, adj);

    // Layer 1: aggregate x [N,8] -> bufA, transform 8->16 -> bufB
    agg_kernel<2><<<(N * 2 + 255) / 256, 256, 0, stream>>>(x, off, adj, dinv, bufA, N, E);
    transform_kernel<8, 16, true><<<(N + 255) / 256, 256, 0, stream>>>(bufA, W1, b1, bufB, N);

    // Layer 2: aggregate h1 [N,16] -> bufA, transform 16->32 -> bufB
    agg_kernel<4><<<(N * 4 + 255) / 256, 256, 0, stream>>>(bufB, off, adj, dinv, bufA, N, E);
    transform_kernel<16, 32, true><<<(N + 255) / 256, 256, 0, stream>>>(bufA, W2, b2, bufB, N);

    // Layer 3: aggregate h2 [N,32] -> bufA, fused transform 32->64 + FC 64->64 -> out
    agg_kernel<8><<<(N * 8 + 255) / 256, 256, 0, stream>>>(bufB, off, adj, dinv, bufA, N, E);
    t3fc_kernel<<<(N / T3_NODES), 256, 0, stream>>>(bufA, W3, b3, Wf, bf, (float*)d_out, N);
}

// Round 5
// 441.991 us; speedup vs baseline: 2.5576x; 1.0347x over previous
//
#include <hip/hip_runtime.h>
#include <hip/hip_bf16.h>

// GCN x3 + FC on a fixed random graph.
//   1. Bucket-partition CSR build (LDS histogram/sort, coalesced global I/O).
//   2. Per layer: pull aggregation in the INPUT dim over PRE-SCALED features
//      y = dinv*h  ->  out[v] = dinv[v]*(sum y[s] + y[v]).  No per-edge dinv
//      gather (R5: halves L2 request count in the hot loop).
//   3. Aggregation loop 4-way unrolled (4 row-gathers in flight per lane).
//   4. Last transform fused with FC (block-cooperative, no per-thread arrays).

#define NB   256     // dst buckets
#define NPB  1024    // nodes per bucket (N = 262144 = NB * NPB)
#define TILE 4096    // edges per partition tile

// ---- P1: global bucket histogram -------------------------------------------
__global__ void hist_kernel(const int* __restrict__ dst, int* __restrict__ ghist,
                            int E, int shift) {
    __shared__ int h[NB];
    int tid = threadIdx.x;
    h[tid] = 0;
    __syncthreads();
    int base = blockIdx.x * TILE;
    int cnt = min(TILE, E - base);
    for (int i = tid; i < cnt; i += 256)
        atomicAdd(&h[dst[base + i] >> shift], 1);
    __syncthreads();
    int v = h[tid];
    if (v) atomicAdd(&ghist[tid], v);
}

// ---- P2: scan bucket counts -> bbase[NB+1], init gcursor -------------------
__global__ void bscan_kernel(const int* __restrict__ ghist, int* __restrict__ bbase,
                             int* __restrict__ gcursor) {
    __shared__ int sh[NB];
    int tid = threadIdx.x;
    int v = ghist[tid];
    sh[tid] = v;
    __syncthreads();
    for (int o = 1; o < NB; o <<= 1) {
        int t = (tid >= o) ? sh[tid - o] : 0;
        __syncthreads();
        sh[tid] += t;
        __syncthreads();
    }
    int incl = sh[tid];
    bbase[tid] = incl - v;
    gcursor[tid] = incl - v;
    if (tid == NB - 1) bbase[NB] = incl;
}

// ---- P3: partition edges into bucket-sorted (src, dst_local) ---------------
__global__ void __launch_bounds__(256)
partition_kernel(const int* __restrict__ src, const int* __restrict__ dst,
                 int* __restrict__ gcursor, int* __restrict__ bsrc,
                 unsigned short* __restrict__ bdl, int E, int shift, int mask) {
    __shared__ int h[NB], st[NB], gp[NB];
    __shared__ unsigned short rk[TILE];
    __shared__ int sd[TILE];
    __shared__ int ss[TILE];
    int tid = threadIdx.x;
    h[tid] = 0;
    __syncthreads();
    int base = blockIdx.x * TILE;
    int cnt = min(TILE, E - base);
    for (int i = tid; i < cnt; i += 256)
        rk[i] = (unsigned short)atomicAdd(&h[dst[base + i] >> shift], 1);
    __syncthreads();
    int hv = h[tid];
    st[tid] = hv;
    __syncthreads();
    for (int o = 1; o < NB; o <<= 1) {
        int t = (tid >= o) ? st[tid - o] : 0;
        __syncthreads();
        st[tid] += t;
        __syncthreads();
    }
    st[tid] -= hv;
    gp[tid] = hv ? atomicAdd(&gcursor[tid], hv) : 0;
    __syncthreads();
    for (int i = tid; i < cnt; i += 256) {
        int d = dst[base + i];
        int b = d >> shift;
        int pos = st[b] + rk[i];
        sd[pos] = d;
        ss[pos] = src[base + i];
    }
    __syncthreads();
    for (int i = tid; i < cnt; i += 256) {
        int d = sd[i];
        int b = d >> shift;
        int g = gp[b] + (i - st[b]);
        bsrc[g] = ss[i];
        bdl[g] = (unsigned short)(d & mask);
    }
}

// ---- P4: per-bucket CSR build: deg -> off/dinv/cursors -> adj --------------
__global__ void __launch_bounds__(256)
build_kernel(const int* __restrict__ bbase, const int* __restrict__ bsrc,
             const unsigned short* __restrict__ bdl,
             int* __restrict__ off, float* __restrict__ dinv, int* __restrict__ adj) {
    __shared__ int deg1[NPB];
    __shared__ int cur[NPB];
    __shared__ int bs[256];
    int tid = threadIdx.x;
    int b = blockIdx.x;
    int s = bbase[b], e = bbase[b + 1];
    int base = tid * 4;
#pragma unroll
    for (int i = 0; i < 4; i++) deg1[base + i] = 0;
    __syncthreads();
    for (int i = s + tid; i < e; i += 256)
        atomicAdd(&deg1[bdl[i]], 1);
    __syncthreads();
    int d0 = deg1[base], d1 = deg1[base + 1], d2 = deg1[base + 2], d3 = deg1[base + 3];
    int th = d0 + d1 + d2 + d3;
    bs[tid] = th;
    __syncthreads();
    for (int o = 1; o < 256; o <<= 1) {
        int t = (tid >= o) ? bs[tid - o] : 0;
        __syncthreads();
        bs[tid] += t;
        __syncthreads();
    }
    int run = s + bs[tid] - th;
    int vb = b * NPB + base;
    off[vb]     = run; cur[base]     = run; dinv[vb]     = rsqrtf((float)(d0 + 1)); run += d0;
    off[vb + 1] = run; cur[base + 1] = run; dinv[vb + 1] = rsqrtf((float)(d1 + 1)); run += d1;
    off[vb + 2] = run; cur[base + 2] = run; dinv[vb + 2] = rsqrtf((float)(d2 + 1)); run += d2;
    off[vb + 3] = run; cur[base + 3] = run; dinv[vb + 3] = rsqrtf((float)(d3 + 1)); run += d3;
    if (b == NB - 1 && tid == 255) off[NB * NPB] = e;   // sentinel: off[N] = E
    __syncthreads();
    for (int i = s + tid; i < e; i += 256) {
        int p = atomicAdd(&cur[bdl[i]], 1);
        adj[p] = bsrc[i];   // scattered only within this bucket's 32KB window
    }
}

// ---- Prescale: y0 = dinv * x  (N x 8) --------------------------------------
__global__ void prescale_kernel(const float* __restrict__ x, const float* __restrict__ dinv,
                                float* __restrict__ y, int n) {
    int v = blockIdx.x * 256 + threadIdx.x;
    if (v >= n) return;
    float dv = dinv[v];
    const float4* xi = (const float4*)(x + (size_t)v * 8);
    float4 a = xi[0], b = xi[1];
    a.x *= dv; a.y *= dv; a.z *= dv; a.w *= dv;
    b.x *= dv; b.y *= dv; b.z *= dv; b.w *= dv;
    float4* yo = (float4*)(y + (size_t)v * 8);
    yo[0] = a; yo[1] = b;
}

// ---- Pull aggregation over pre-scaled features -----------------------------
// out[v] = dinv[v] * (sum_{s in in(v)} y[s] + y[v]);  y = dinv*h.
// C float4-chunks per row; 4-way unrolled gather for MLP.
template <int C>
__global__ void __launch_bounds__(256)
agg_kernel(const float* __restrict__ y, const int* __restrict__ off,
           const int* __restrict__ adj, const float* __restrict__ dinv,
           float* __restrict__ out, int n) {
    int t = blockIdx.x * blockDim.x + threadIdx.x;
    int v = t / C;
    int c = t % C;
    if (v >= n) return;
    const float4* y4 = (const float4*)y;
    int beg = off[v];
    int end = off[v + 1];
    float4 a0 = y4[(size_t)v * C + c];          // self term
    float4 a1, a2, a3;
    a1.x = a1.y = a1.z = a1.w = 0.f;
    a2.x = a2.y = a2.z = a2.w = 0.f;
    a3.x = a3.y = a3.z = a3.w = 0.f;
    int e = beg;
    for (; e + 4 <= end; e += 4) {
        int s0 = adj[e], s1 = adj[e + 1], s2 = adj[e + 2], s3 = adj[e + 3];
        float4 x0 = y4[(size_t)s0 * C + c];
        float4 x1 = y4[(size_t)s1 * C + c];
        float4 x2 = y4[(size_t)s2 * C + c];
        float4 x3 = y4[(size_t)s3 * C + c];
        a0.x += x0.x; a0.y += x0.y; a0.z += x0.z; a0.w += x0.w;
        a1.x += x1.x; a1.y += x1.y; a1.z += x1.z; a1.w += x1.w;
        a2.x += x2.x; a2.y += x2.y; a2.z += x2.z; a2.w += x2.w;
        a3.x += x3.x; a3.y += x3.y; a3.z += x3.z; a3.w += x3.w;
    }
    for (; e < end; e++) {
        float4 xs = y4[(size_t)adj[e] * C + c];
        a1.x += xs.x; a1.y += xs.y; a1.z += xs.z; a1.w += xs.w;
    }
    float wv = dinv[v];
    float4 o;
    o.x = ((a0.x + a1.x) + (a2.x + a3.x)) * wv;
    o.y = ((a0.y + a1.y) + (a2.y + a3.y)) * wv;
    o.z = ((a0.z + a1.z) + (a2.z + a3.z)) * wv;
    o.w = ((a0.w + a1.w) + (a2.w + a3.w)) * wv;
    ((float4*)out)[(size_t)v * C + c] = o;
}

// ---- Dense per-node transform, epilogue pre-scales by dinv -----------------
// out[v] = dinv[v] * relu(in[v] @ W + b)   (y for the next aggregation)
template <int FIN, int FOUT>
__global__ void transform_kernel(const float* __restrict__ in, const float* __restrict__ W,
                                 const float* __restrict__ b, const float* __restrict__ dinv,
                                 float* __restrict__ out, int n) {
    __shared__ float Ws[FIN * FOUT];
    __shared__ float bs[FOUT];
    for (int i = threadIdx.x; i < FIN * FOUT; i += blockDim.x) Ws[i] = W[i];
    if (threadIdx.x < FOUT) bs[threadIdx.x] = b[threadIdx.x];
    __syncthreads();
    int v = blockIdx.x * blockDim.x + threadIdx.x;
    if (v >= n) return;
    float a[FIN];
    const float4* in4 = (const float4*)(in + (size_t)v * FIN);
#pragma unroll
    for (int k = 0; k < FIN / 4; k++) {
        float4 t = in4[k];
        a[4 * k] = t.x; a[4 * k + 1] = t.y; a[4 * k + 2] = t.z; a[4 * k + 3] = t.w;
    }
    float dv = dinv[v];
    float4* out4 = (float4*)(out + (size_t)v * FOUT);
#pragma unroll
    for (int j = 0; j < FOUT; j += 4) {
        float acc0 = bs[j], acc1 = bs[j + 1], acc2 = bs[j + 2], acc3 = bs[j + 3];
#pragma unroll
        for (int k = 0; k < FIN; k++) {
            float xv = a[k];
            acc0 += xv * Ws[k * FOUT + j];
            acc1 += xv * Ws[k * FOUT + j + 1];
            acc2 += xv * Ws[k * FOUT + j + 2];
            acc3 += xv * Ws[k * FOUT + j + 3];
        }
        float4 o;
        o.x = dv * fmaxf(acc0, 0.f); o.y = dv * fmaxf(acc1, 0.f);
        o.z = dv * fmaxf(acc2, 0.f); o.w = dv * fmaxf(acc3, 0.f);
        out4[j / 4] = o;
    }
}

// ---- Fused layer-3 transform + FC (block-cooperative) ----------------------
#define T3_NODES 32
__global__ void __launch_bounds__(256)
t3fc_kernel(const float* __restrict__ in,
            const float* __restrict__ W3, const float* __restrict__ b3,
            const float* __restrict__ Wf, const float* __restrict__ bf,
            float* __restrict__ out, int n) {
    __shared__ float W3s[32 * 64];
    __shared__ float Wfs[64 * 64];
    __shared__ float b3s[64], bfs[64];
    __shared__ float ins[T3_NODES][33];
    __shared__ float tts[T3_NODES][65];
    const int tid = threadIdx.x;
    for (int i = tid; i < 32 * 64; i += 256) W3s[i] = W3[i];
    for (int i = tid; i < 64 * 64; i += 256) Wfs[i] = Wf[i];
    if (tid < 64) { b3s[tid] = b3[tid]; bfs[tid] = bf[tid]; }
    const int vbase = blockIdx.x * T3_NODES;
    {
        const float4* g = (const float4*)(in + (size_t)vbase * 32);
        float4 t = g[tid];
        int v = tid >> 3, c = (tid & 7) * 4;
        ins[v][c] = t.x; ins[v][c + 1] = t.y; ins[v][c + 2] = t.z; ins[v][c + 3] = t.w;
    }
    __syncthreads();
    const int tx = tid & 15;
    const int ty = tid >> 4;
    const int j0 = tx * 4;
    {
        float a00 = b3s[j0], a01 = b3s[j0 + 1], a02 = b3s[j0 + 2], a03 = b3s[j0 + 3];
        float a10 = a00, a11 = a01, a12 = a02, a13 = a03;
#pragma unroll
        for (int k = 0; k < 32; k++) {
            float4 w = *(const float4*)&W3s[k * 64 + j0];
            float x0 = ins[ty][k];
            float x1 = ins[ty + 16][k];
            a00 += x0 * w.x; a01 += x0 * w.y; a02 += x0 * w.z; a03 += x0 * w.w;
            a10 += x1 * w.x; a11 += x1 * w.y; a12 += x1 * w.z; a13 += x1 * w.w;
        }
        tts[ty][j0]          = fmaxf(a00, 0.f); tts[ty][j0 + 1]      = fmaxf(a01, 0.f);
        tts[ty][j0 + 2]      = fmaxf(a02, 0.f); tts[ty][j0 + 3]      = fmaxf(a03, 0.f);
        tts[ty + 16][j0]     = fmaxf(a10, 0.f); tts[ty + 16][j0 + 1] = fmaxf(a11, 0.f);
        tts[ty + 16][j0 + 2] = fmaxf(a12, 0.f); tts[ty + 16][j0 + 3] = fmaxf(a13, 0.f);
    }
    __syncthreads();
    {
        float a00 = bfs[j0], a01 = bfs[j0 + 1], a02 = bfs[j0 + 2], a03 = bfs[j0 + 3];
        float a10 = a00, a11 = a01, a12 = a02, a13 = a03;
#pragma unroll
        for (int k = 0; k < 64; k++) {
            float4 w = *(const float4*)&Wfs[k * 64 + j0];
            float x0 = tts[ty][k];
            float x1 = tts[ty + 16][k];
            a00 += x0 * w.x; a01 += x0 * w.y; a02 += x0 * w.z; a03 += x0 * w.w;
            a10 += x1 * w.x; a11 += x1 * w.y; a12 += x1 * w.z; a13 += x1 * w.w;
        }
        float4 o0; o0.x = a00; o0.y = a01; o0.z = a02; o0.w = a03;
        float4 o1; o1.x = a10; o1.y = a11; o1.z = a12; o1.w = a13;
        *(float4*)(out + ((size_t)(vbase + ty)) * 64 + j0) = o0;
        *(float4*)(out + ((size_t)(vbase + ty + 16)) * 64 + j0) = o1;
    }
}

extern "C" void kernel_launch(void* const* d_in, const int* in_sizes, int n_in,
                              void* d_out, int out_size, void* d_ws, size_t ws_size,
                              hipStream_t stream) {
    const float* x  = (const float*)d_in[0];
    const float* W1 = (const float*)d_in[1];
    const float* b1 = (const float*)d_in[2];
    const float* W2 = (const float*)d_in[3];
    const float* b2 = (const float*)d_in[4];
    const float* W3 = (const float*)d_in[5];
    const float* b3 = (const float*)d_in[6];
    const float* Wf = (const float*)d_in[7];
    const float* bf = (const float*)d_in[8];
    const int*   ei = (const int*)d_in[9];

    const int N = in_sizes[0] / 8;   // 262144
    const int E = in_sizes[9] / 2;   // 2097152
    const int* srcv = ei;
    const int* dstv = ei + E;
    const int shift = 10;            // log2(NPB)

    // Workspace layout
    char* p = (char*)d_ws;
    int*   off    = (int*)p;            p += (size_t)(N + 1) * 4;
    float* dinv   = (float*)p;          p += (size_t)N * 4;
    int*   adj    = (int*)p;            p += (size_t)E * 4;
    int*   ghist  = (int*)p;            p += NB * 4;
    int*   bbase  = (int*)p;            p += (NB + 1) * 4;
    int*   gcur   = (int*)p;            p += NB * 4 + 4;
    float* bufA   = (float*)p;          p += (size_t)N * 32 * 4;
    float* bufB   = (float*)p;          p += (size_t)N * 32 * 4;
    // binned edge arrays alias bufB (dead until transform1 writes y1 there)
    int*            bsrc = (int*)bufB;
    unsigned short* bdl  = (unsigned short*)(bufB + (size_t)E);
    // y0 aliases bufA's upper region (dead once agg<4> runs; agg<2> writes [0,N*8))
    float* y0 = bufA + (size_t)N * 8;

    hipMemsetAsync(ghist, 0, NB * 4, stream);

    int nt = (E + TILE - 1) / TILE;  // 512 tiles
    hist_kernel<<<nt, 256, 0, stream>>>(dstv, ghist, E, shift);
    bscan_kernel<<<1, NB, 0, stream>>>(ghist, bbase, gcur);
    partition_kernel<<<nt, 256, 0, stream>>>(srcv, dstv, gcur, bsrc, bdl, E, shift, NPB - 1);
    build_kernel<<<NB, 256, 0, stream>>>(bbase, bsrc, bdl, off, dinv, adj);

    prescale_kernel<<<(N + 255) / 256, 256, 0, stream>>>(x, dinv, y0, N);

    // Layer 1: aggregate y0 [N,8] -> a1 = bufA[0,N*8), transform 8->16 -> y1 = bufB
    agg_kernel<2><<<(N * 2 + 255) / 256, 256, 0, stream>>>(y0, off, adj, dinv, bufA, N);
    transform_kernel<8, 16><<<(N + 255) / 256, 256, 0, stream>>>(bufA, W1, b1, dinv, bufB, N);

    // Layer 2: aggregate y1 [N,16] -> a2 = bufA, transform 16->32 -> y2 = bufB
    agg_kernel<4><<<(N * 4 + 255) / 256, 256, 0, stream>>>(bufB, off, adj, dinv, bufA, N);
    transform_kernel<16, 32><<<(N + 255) / 256, 256, 0, stream>>>(bufA, W2, b2, dinv, bufB, N);

    // Layer 3: aggregate y2 [N,32] -> a3 = bufA, fused transform+FC -> out
    agg_kernel<8><<<(N * 8 + 255) / 256, 256, 0, stream>>>(bufB, off, adj, dinv, bufA, N);
    t3fc_kernel<<<(N / T3_NODES), 256, 0, stream>>>(bufA, W3, b3, Wf, bf, (float*)d_out, N);
}